// Round 1
// 279.134 us; speedup vs baseline: 1.1503x; 1.1503x over previous
//
#include <hip/hip_runtime.h>
#include <hip/hip_bf16.h>

// B=8, N=4096, D=H=256. out[b,h] = sum_k w[b,k]*V[b,k,h],
//   w[b,k] = (1/N) sum_q exp(scale*s_qk)/l_q,  l_q = sum_k exp(scale*s_qk)
// R11: score passes restructured to A-in-registers + streamed double-buffered B.
//      Each wave caches 32 A-rows x 256 depth as 16 MFMA frags (loaded once);
//      only the B tile (64 rows x 256) streams through LDS (2-deep dbuf,
//      global_load_lds w=16, one __syncthreads per tile). Wave-local column
//      reduction via shfl_xor butterfly. XCD-chunked block remap keeps the
//      16 blocks sharing a stream slice on one XCD (L2-served re-reads).
//      qkv/convert/finalize kernels kept verbatim from the validated R10.

#define NTOK 4096
#define HDIM 256
#define NBATCH 8
#define SCALE 0.0625f  // 1/sqrt(256)

typedef __attribute__((ext_vector_type(8))) short short8_t;   // 8 bf16 (4 VGPRs)
typedef __attribute__((ext_vector_type(16))) float f32x16;    // 32x32 C/D frag

__device__ __forceinline__ unsigned short f2bf(float f) {
    unsigned u = __float_as_uint(f);
    u += 0x7fff + ((u >> 16) & 1);   // RNE
    return (unsigned short)(u >> 16);
}

#define MFMA(a, b, c) __builtin_amdgcn_mfma_f32_32x32x16_bf16(a, b, c, 0, 0, 0)

__device__ __forceinline__ void async_cp16(const void* g, void* l) {
    __builtin_amdgcn_global_load_lds((const __attribute__((address_space(1))) void*)g,
                                     (__attribute__((address_space(3))) void*)l, 16, 0, 0);
}

// ---- validated 128-row stager (used by qkv_mfma): 16B unit (r,u) -> r*8 + (u^(r&7))
__device__ __forceinline__ void stage_swz(unsigned short* lds, const unsigned short* src,
                                          int row0, int dbase, int w, int l) {
#pragma unroll
    for (int i = 0; i < 4; ++i) {
        int rloc = w * 32 + i * 8 + (l >> 3);
        int u = (l & 7) ^ (l >> 3);
        const unsigned short* g = src + (size_t)(row0 + rloc) * HDIM + dbase + u * 8;
        unsigned short* d = lds + (w * 32 + i * 8) * 64;
        async_cp16(g, d);
    }
}

__device__ __forceinline__ short8_t frd(const unsigned short* lds, int rb, int lo, int u) {
    return *(const short8_t*)(lds + ((rb * 32 + lo) * 8 + (u ^ (lo & 7))) * 8);
}

// ---- R11 stager: 64 rows x 256 bf16 (32KB) resident tile, layout [dc][row][unit'],
//      unit' = u ^ (row&7). 512 threads, 4 x 16B per thread, wave-uniform LDS dest.
__device__ __forceinline__ void stage64(unsigned short* lds, const unsigned short* src,
                                        int w, int l) {
#pragma unroll
    for (int j = 0; j < 4; ++j) {
        int base = (w * 4 + j) * 64;          // 16B-unit index of lane 0
        int idx = base + l;
        int r = (idx >> 3) & 63;
        int dc = idx >> 9;
        int u = (idx & 7) ^ (r & 7);
        const unsigned short* g = src + (size_t)r * HDIM + dc * 64 + u * 8;
        async_cp16(g, lds + base * 8);
    }
}

// read B-frag: row r (0..63) of resident tile, depth unit u (0..31)
__device__ __forceinline__ short8_t krd(const unsigned short* lds, int r, int u) {
    int dc = u >> 3, uu = u & 7;
    return *(const short8_t*)(lds + ((dc * 64 + r) * 8 + (uu ^ (r & 7))) * 8);
}

__global__ void zero_kernel(float* __restrict__ w, float* __restrict__ l, float* __restrict__ out) {
    int i = blockIdx.x * 256 + threadIdx.x;
    w[i] = 0.f;
    l[i] = 0.f;
    if (i < NBATCH * HDIM) out[i] = 0.f;
}

// ---------------- fp32 -> bf16 for x (once) ----------------
__global__ void convert_x(const float* __restrict__ x, unsigned short* __restrict__ xbf) {
    int i = (blockIdx.x * 256 + threadIdx.x) * 4;
    float4 v = *(const float4*)(x + i);
    ushort4 o;
    o.x = f2bf(v.x); o.y = f2bf(v.y); o.z = f2bf(v.z); o.w = f2bf(v.w);
    *(ushort4*)(xbf + i) = o;
}

__global__ void convert_wt(const float* __restrict__ Wq, const float* __restrict__ Wk,
                           const float* __restrict__ Wv, unsigned short* __restrict__ Wt) {
    int z = blockIdx.y;
    const float* W = (z == 0) ? Wq : (z == 1) ? Wk : Wv;
    unsigned short* o = Wt + z * 65536;
    int n = threadIdx.x;
    for (int kk = 0; kk < 32; ++kk) {
        int k = blockIdx.x * 32 + kk;
        o[n * 256 + k] = f2bf(W[k * 256 + n]);
    }
}

// ---------------- QKV projection (verbatim validated) ----------------
__global__ __launch_bounds__(256) void qkv_mfma(const unsigned short* __restrict__ xbf,
                                                const unsigned short* __restrict__ Wt,
                                                const float* __restrict__ bq, const float* __restrict__ bk,
                                                const float* __restrict__ bv,
                                                unsigned short* __restrict__ Qbf,
                                                unsigned short* __restrict__ Kbf,
                                                float* __restrict__ Vf) {
    const int z = blockIdx.z;
    const unsigned short* Wz = Wt + z * 65536;
    const float* bias = (z == 0) ? bq : (z == 1) ? bk : bv;
    const int m0 = blockIdx.x * 128, n0 = blockIdx.y * 128;
    const int t = threadIdx.x, w = t >> 6, l = t & 63, lo = l & 31, hi = l >> 5;
    const int rm = (w & 1) * 2, rn = (w >> 1) * 2;

    __shared__ __align__(16) char smem[32768];   // Xb 16K | Wb 16K
    unsigned short* Xb = (unsigned short*)smem;
    unsigned short* Wb = (unsigned short*)(smem + 16384);

    f32x16 acc[2][2];
#pragma unroll
    for (int a = 0; a < 2; ++a)
#pragma unroll
        for (int c = 0; c < 2; ++c)
#pragma unroll
            for (int r = 0; r < 16; ++r) acc[a][c][r] = 0.f;

    for (int dc = 0; dc < 4; ++dc) {
        __syncthreads();
        stage_swz(Xb, xbf, m0, dc * 64, w, l);
        stage_swz(Wb, Wz, n0, dc * 64, w, l);
        __syncthreads();
#pragma unroll
        for (int ks = 0; ks < 4; ++ks) {
            int u = ks * 2 + hi;
            short8_t a0 = frd(Xb, rm + 0, lo, u);
            short8_t a1 = frd(Xb, rm + 1, lo, u);
            short8_t b0 = frd(Wb, rn + 0, lo, u);
            short8_t b1 = frd(Wb, rn + 1, lo, u);
            acc[0][0] = MFMA(a0, b0, acc[0][0]);
            acc[0][1] = MFMA(a0, b1, acc[0][1]);
            acc[1][0] = MFMA(a1, b0, acc[1][0]);
            acc[1][1] = MFMA(a1, b1, acc[1][1]);
        }
    }
    float bc0 = bias[n0 + (w >> 1) * 64 + lo];
    float bc1 = bias[n0 + (w >> 1) * 64 + 32 + lo];
#pragma unroll
    for (int mb = 0; mb < 2; ++mb)
#pragma unroll
        for (int r = 0; r < 16; ++r) {
            int row = m0 + (w & 1) * 64 + mb * 32 + (r & 3) + 8 * (r >> 2) + 4 * hi;
            int c0 = n0 + (w >> 1) * 64 + lo, c1 = c0 + 32;
            float v0 = acc[mb][0][r] + bc0;
            float v1 = acc[mb][1][r] + bc1;
            if (z == 2) {
                Vf[(size_t)row * HDIM + c0] = v0;
                Vf[(size_t)row * HDIM + c1] = v1;
            } else {
                unsigned short* o = (z == 0) ? Qbf : Kbf;
                o[(size_t)row * HDIM + c0] = f2bf(v0);
                o[(size_t)row * HDIM + c1] = f2bf(v1);
            }
        }
}

// ---------------- pass 1 (R11): l[b,q] = sum_k exp(scale*s) ----------------
// Block: 512 thr / 8 waves. Wave w owns q-rows q0+w*32 (A-frags in regs).
// Streams 2048 K-rows in 32 tiles of 64 (LDS dbuf), 1 barrier per tile.
__global__ __launch_bounds__(512, 2) void score_pass1(const unsigned short* __restrict__ Qbf,
                                                      const unsigned short* __restrict__ Kbf,
                                                      float* __restrict__ lsum) {
    // XCD-chunked remap: the 16 q-tile blocks sharing one (kslice,b) K-stream
    // land on one XCD (ids congruent mod 8) -> stream re-reads are L2-hits.
    const int id = blockIdx.x;
    const int xcd = id & 7, j = id >> 3;        // j in 0..31
    const int qtile = j & 15, gh = j >> 4;      // gh in 0..1
    const int g = xcd * 2 + gh;                 // group 0..15
    const int kslice = g & 1, b = g >> 1;

    const int q0 = qtile * 256;
    const int kbase = kslice * 2048;
    const int t = threadIdx.x, w = t >> 6, l = t & 63, lo = l & 31, hi = l >> 5;
    const unsigned short* Qb = Qbf + (size_t)b * NTOK * HDIM;
    const unsigned short* Kb = Kbf + (size_t)b * NTOK * HDIM;

    __shared__ __align__(16) unsigned short Kbuf[2][16384];   // 2 x 32KB

    stage64(Kbuf[0], Kb + (size_t)kbase * HDIM, w, l);        // tile 0 in flight

    // A-frags: 32 q-rows x 256 depth, MFMA A layout (row=lo, k=hi*8+j)
    short8_t A[16];
    const unsigned short* qrow = Qb + (size_t)(q0 + w * 32 + lo) * HDIM + hi * 8;
#pragma unroll
    for (int st = 0; st < 16; ++st) A[st] = *(const short8_t*)(qrow + st * 16);

    float rs[16];
#pragma unroll
    for (int r = 0; r < 16; ++r) rs[r] = 0.f;

    __syncthreads();   // drains tile-0 stage + A-loads

    int cur = 0;
    for (int kt = 0; kt < 32; ++kt) {
        if (kt < 31) stage64(Kbuf[cur ^ 1], Kb + (size_t)(kbase + (kt + 1) * 64) * HDIM, w, l);
        const unsigned short* KL = Kbuf[cur];
        f32x16 acc0, acc1;
#pragma unroll
        for (int r = 0; r < 16; ++r) { acc0[r] = 0.f; acc1[r] = 0.f; }
#pragma unroll
        for (int st = 0; st < 16; ++st) {
            int u = st * 2 + hi;
            short8_t b0 = krd(KL, lo, u);
            short8_t b1 = krd(KL, 32 + lo, u);
            acc0 = MFMA(A[st], b0, acc0);
            acc1 = MFMA(A[st], b1, acc1);
        }
#pragma unroll
        for (int r = 0; r < 16; ++r)
            rs[r] += __expf(acc0[r] * SCALE) + __expf(acc1[r] * SCALE);
        __syncthreads();   // tile kt reads done; tile kt+1 staged (vmcnt(0))
        cur ^= 1;
    }

    // column reduce over the 32 lo-lanes (each lane held k-cols lo and 32+lo)
#pragma unroll
    for (int r = 0; r < 16; ++r) {
        float v = rs[r];
        v += __shfl_xor(v, 1);
        v += __shfl_xor(v, 2);
        v += __shfl_xor(v, 4);
        v += __shfl_xor(v, 8);
        v += __shfl_xor(v, 16);
        rs[r] = v;
    }
    if (lo == 0) {
#pragma unroll
        for (int r = 0; r < 16; ++r) {
            int row = q0 + w * 32 + (r & 3) + 8 * (r >> 2) + 4 * hi;
            atomicAdd(&lsum[b * NTOK + row], rs[r]);
        }
    }
}

// ---------------- pass 2 (R11): w[b,k] += sum_q exp(scale*s)/l_q ----------------
// Mirror of pass 1: wave owns 32 K-rows (A-frags), Q streams through LDS.
__global__ __launch_bounds__(512, 2) void score_pass2(const unsigned short* __restrict__ Qbf,
                                                      const unsigned short* __restrict__ Kbf,
                                                      const float* __restrict__ lsum,
                                                      float* __restrict__ wsum) {
    const int id = blockIdx.x;
    const int xcd = id & 7, j = id >> 3;
    const int ktile = j & 15, gh = j >> 4;
    const int g = xcd * 2 + gh;
    const int qslice = g & 1, b = g >> 1;

    const int k0 = ktile * 256;
    const int qbase = qslice * 2048;
    const int t = threadIdx.x, w = t >> 6, l = t & 63, lo = l & 31, hi = l >> 5;
    const unsigned short* Qb = Qbf + (size_t)b * NTOK * HDIM;
    const unsigned short* Kb = Kbf + (size_t)b * NTOK * HDIM;
    const float* lb = lsum + (size_t)b * NTOK;

    __shared__ __align__(16) unsigned short Qbuf[2][16384];

    stage64(Qbuf[0], Qb + (size_t)qbase * HDIM, w, l);

    short8_t A[16];
    const unsigned short* krow = Kb + (size_t)(k0 + w * 32 + lo) * HDIM + hi * 8;
#pragma unroll
    for (int st = 0; st < 16; ++st) A[st] = *(const short8_t*)(krow + st * 16);

    float cs[16];
#pragma unroll
    for (int r = 0; r < 16; ++r) cs[r] = 0.f;

    __syncthreads();

    int cur = 0;
    for (int qt = 0; qt < 32; ++qt) {
        if (qt < 31) stage64(Qbuf[cur ^ 1], Qb + (size_t)(qbase + (qt + 1) * 64) * HDIM, w, l);
        float linv0 = 1.0f / lb[qbase + qt * 64 + lo];
        float linv1 = 1.0f / lb[qbase + qt * 64 + 32 + lo];
        const unsigned short* QL = Qbuf[cur];
        f32x16 acc0, acc1;
#pragma unroll
        for (int r = 0; r < 16; ++r) { acc0[r] = 0.f; acc1[r] = 0.f; }
#pragma unroll
        for (int st = 0; st < 16; ++st) {
            int u = st * 2 + hi;
            short8_t b0 = krd(QL, lo, u);        // q-cols qt*64 + lo
            short8_t b1 = krd(QL, 32 + lo, u);   // q-cols qt*64 + 32 + lo
            acc0 = MFMA(A[st], b0, acc0);
            acc1 = MFMA(A[st], b1, acc1);
        }
#pragma unroll
        for (int r = 0; r < 16; ++r)
            cs[r] += __expf(acc0[r] * SCALE) * linv0 + __expf(acc1[r] * SCALE) * linv1;
        __syncthreads();
        cur ^= 1;
    }

#pragma unroll
    for (int r = 0; r < 16; ++r) {
        float v = cs[r];
        v += __shfl_xor(v, 1);
        v += __shfl_xor(v, 2);
        v += __shfl_xor(v, 4);
        v += __shfl_xor(v, 8);
        v += __shfl_xor(v, 16);
        cs[r] = v;
    }
    if (lo == 0) {
#pragma unroll
        for (int r = 0; r < 16; ++r) {
            int row = k0 + w * 32 + (r & 3) + 8 * (r >> 2) + 4 * hi;
            atomicAdd(&wsum[b * NTOK + row], cs[r]);
        }
    }
}

__global__ __launch_bounds__(256) void finalize_kernel(const float* __restrict__ V,
                                                       const float* __restrict__ w,
                                                       float* __restrict__ out) {
    const int b = blockIdx.y;
    const int k0 = blockIdx.x * 256;
    const int h = threadIdx.x;
    __shared__ float wsh[256];
    wsh[h] = w[b * NTOK + k0 + h];
    __syncthreads();
    const float* Vb = V + ((size_t)b * NTOK + k0) * HDIM;
    float acc = 0.f;
#pragma unroll 4
    for (int kk = 0; kk < 256; ++kk) acc = fmaf(wsh[kk], Vb[(size_t)kk * HDIM + h], acc);
    atomicAdd(&out[b * HDIM + h], acc * (1.0f / (float)NTOK));
}

extern "C" void kernel_launch(void* const* d_in, const int* in_sizes, int n_in,
                              void* d_out, int out_size, void* d_ws, size_t ws_size,
                              hipStream_t stream) {
    const float* x  = (const float*)d_in[0];
    const float* Wq = (const float*)d_in[1];
    const float* bq = (const float*)d_in[2];
    const float* Wk = (const float*)d_in[3];
    const float* bk = (const float*)d_in[4];
    const float* Wv = (const float*)d_in[5];
    const float* bv = (const float*)d_in[6];
    float* out = (float*)d_out;

    const size_t BNH = (size_t)NBATCH * NTOK * HDIM;   // 8388608
    unsigned short* Wt  = (unsigned short*)d_ws;        // 3 transposed bf16 weights
    unsigned short* xbf = Wt + 3 * 65536;               // bf16 x
    unsigned short* Qbf = xbf + BNH;
    unsigned short* Kbf = Qbf + BNH;
    float* Vf   = (float*)(Kbf + BNH);                  // fp32 V
    float* lsum = Vf + BNH;
    float* wsum = lsum + (size_t)NBATCH * NTOK;

    zero_kernel<<<dim3(128), dim3(256), 0, stream>>>(wsum, lsum, out);
    convert_x<<<dim3(8192), dim3(256), 0, stream>>>(x, xbf);
    convert_wt<<<dim3(8, 3), dim3(256), 0, stream>>>(Wq, Wk, Wv, Wt);
    qkv_mfma<<<dim3(256, 2, 3), dim3(256), 0, stream>>>(xbf, Wt, bq, bk, bv, Qbf, Kbf, Vf);
    score_pass1<<<dim3(256), dim3(512), 0, stream>>>(Qbf, Kbf, lsum);
    score_pass2<<<dim3(256), dim3(512), 0, stream>>>(Qbf, Kbf, lsum, wsum);
    finalize_kernel<<<dim3(16, 8), dim3(256), 0, stream>>>(Vf, wsum, out);
}